// Round 6
// baseline (740.272 us; speedup 1.0000x reference)
//
#include <hip/hip_runtime.h>

// MoE_77644418777543 — round 13.
// r12 post-mortem: 2-phase dbuf REGRESSED (71->75us): LDS 25->49.7KB cut
// occupancy 31->20.7%, and a 1-deep prefetch window (~250cy compute) can't
// hide ~500-900cy load latency; absmax also drifted (possible barrier race).
// REVERT to serial 2-barrier loop. The real lever per the m97 ladder: tile
// size. 64x128 has 16 MFMA/K-tile/wave (MFMA:ds_read 1.33); m97's 128x128
// has 32 (ratio 2.0) and is proven at 874-912 TF with this exact serial
// structure. This round: 128x128 tile, BK=64, 4 waves x (64x64 quadrant,
// 4x4 fragments, 64 acc VGPRs), worklist granularity 128 rows, OUTBF
// epilogue restaged in two 64-row halves (LDS stays 32KB -> 3-4 blocks/CU).
//
// Workspace (MB = 2^20), aliased by liveness:
//   0-8M    combined fp32            (gate concat; then dead)
//   8-12M   cbf bf16                 (dead after expert GEMM1)
//   12-28M  w1t bf16 [16][1024][512] (dead after GEMM1) / fusedb@12M, obuf@20M after
//   29-61M  w2t bf16 [16][1024][1024](dead after GEMM2)
//   61M     wq / rows / counts / wl[8][1024] / topk u32[4096]
//   62M     w2tg fp32 [16][1024] (gate w2 transposed, 64KB)
//   63-64M  fw1t bf16 [512][1024]
//   65-97M  h1bf bf16 [16384][1024]  (written by expert GEMM1)
//     65-77M  cbf3 bf16 [4096][1536]  (dead after gate MFMA -> safe alias)
//     77-80M  w1t3 bf16 [1024][1536]  (dead after gate MFMA -> safe alias)
//   99-131M gbuf fp32 (dead after ln_topk) then h2b bf16 [16384][1024]

#define EPSN 1e-5f

typedef __attribute__((ext_vector_type(8))) short v8s;   // 8 bf16 (4 VGPRs)
typedef __attribute__((ext_vector_type(4))) float v4f;   // 4 fp32 acc

typedef const unsigned int __attribute__((address_space(1)))* gas_u32;
typedef unsigned int __attribute__((address_space(3)))* las_u32;

__device__ __forceinline__ void glds16(const void* g, const void* l) {
    __builtin_amdgcn_global_load_lds((gas_u32)(uintptr_t)g, (las_u32)(uintptr_t)l, 16, 0, 0);
}

__device__ __forceinline__ float gelu_f(float x) {
    return 0.5f * x * (1.0f + erff(x * 0.70710678118654752440f));
}
__device__ __forceinline__ unsigned short f2bf(float x) {
    unsigned int u = __float_as_uint(x);
    u += 0x7fffu + ((u >> 16) & 1u);
    return (unsigned short)(u >> 16);
}
__device__ __forceinline__ float bf2f(unsigned short u) {
    return __uint_as_float(((unsigned int)u) << 16);
}

// concat wifi|rfid -> combined fp32; bf16 copy for expert GEMM1; and
// bf16x3 row [hi(512) | lo(512) | hi(512)] for the split-precision gate GEMM.
__global__ __launch_bounds__(256) void concat_kernel(const float4* __restrict__ wifi,
                                                     const float4* __restrict__ rfid,
                                                     float4* __restrict__ comb,
                                                     ushort4* __restrict__ cbf,
                                                     ushort4* __restrict__ cbf3) {
    int gid = blockIdx.x * 256 + threadIdx.x;   // 4096 * 128
    int b = gid >> 7, c = gid & 127;
    float4 v = (c < 64) ? wifi[b * 64 + c] : rfid[b * 64 + (c - 64)];
    comb[gid] = v;
    ushort4 hi, lo;
    hi.x = f2bf(v.x); hi.y = f2bf(v.y); hi.z = f2bf(v.z); hi.w = f2bf(v.w);
    lo.x = f2bf(v.x - bf2f(hi.x));
    lo.y = f2bf(v.y - bf2f(hi.y));
    lo.z = f2bf(v.z - bf2f(hi.z));
    lo.w = f2bf(v.w - bf2f(hi.w));
    cbf[gid] = hi;
    const long r3 = (long)b * 384 + c;          // 1536 ush row = 384 ushort4
    cbf3[r3]       = hi;
    cbf3[r3 + 128] = lo;
    cbf3[r3 + 256] = hi;
}

// in: per-expert [K][N] fp32 -> out: per-expert [N][K] bf16 (transpose+convert)
__global__ __launch_bounds__(256) void transpose_f2b(const float* __restrict__ in,
                                                     unsigned short* __restrict__ out,
                                                     int K, int N) {
    __shared__ float t[64][65];
    int e = blockIdx.z;
    int n0 = blockIdx.x << 6, k0 = blockIdx.y << 6;
    const float* ie = in + (long)e * K * N;
    unsigned short* oe = out + (long)e * N * K;
    int tid = threadIdx.x;
    int rr = tid >> 4, cc = (tid & 15) << 2;
#pragma unroll
    for (int p = 0; p < 4; ++p) {
        int k = (p << 4) + rr;
        float4 v = *(const float4*)(ie + (long)(k0 + k) * N + n0 + cc);
        t[k][cc + 0] = v.x; t[k][cc + 1] = v.y; t[k][cc + 2] = v.z; t[k][cc + 3] = v.w;
    }
    __syncthreads();
    int n = tid >> 2, kq = (tid & 3) << 4;
    unsigned short u[16];
#pragma unroll
    for (int j = 0; j < 16; ++j) u[j] = f2bf(t[kq + j][n]);
    uint4* dst = (uint4*)(oe + (long)(n0 + n) * K + k0 + kq);
    dst[0] = ((const uint4*)u)[0];
    dst[1] = ((const uint4*)u)[1];
}

// gate_w1 [K=512][N=1024] fp32 -> w1t3 [N][3K=1536] bf16, rows [hi | hi | lo]
__global__ __launch_bounds__(256) void transpose_f2b_hilo(const float* __restrict__ in,
                                                          unsigned short* __restrict__ out,
                                                          int K, int N) {
    __shared__ float t[64][65];
    int n0 = blockIdx.x << 6, k0 = blockIdx.y << 6;
    int tid = threadIdx.x;
    int rr = tid >> 4, cc = (tid & 15) << 2;
#pragma unroll
    for (int p = 0; p < 4; ++p) {
        int k = (p << 4) + rr;
        float4 v = *(const float4*)(in + (long)(k0 + k) * N + n0 + cc);
        t[k][cc + 0] = v.x; t[k][cc + 1] = v.y; t[k][cc + 2] = v.z; t[k][cc + 3] = v.w;
    }
    __syncthreads();
    int n = tid >> 2, kq = (tid & 3) << 4;
    unsigned short uh[16], ul[16];
#pragma unroll
    for (int j = 0; j < 16; ++j) {
        float x = t[kq + j][n];
        unsigned short h = f2bf(x);
        uh[j] = h;
        ul[j] = f2bf(x - bf2f(h));
    }
    unsigned short* dh = out + (long)(n0 + n) * (3 * K) + k0 + kq;
    ((uint4*)dh)[0]           = ((const uint4*)uh)[0];
    ((uint4*)dh)[1]           = ((const uint4*)uh)[1];
    ((uint4*)(dh + K))[0]     = ((const uint4*)uh)[0];
    ((uint4*)(dh + K))[1]     = ((const uint4*)uh)[1];
    ((uint4*)(dh + 2 * K))[0] = ((const uint4*)ul)[0];
    ((uint4*)(dh + 2 * K))[1] = ((const uint4*)ul)[1];
}

// gate_w2 fp32 [1024][16] -> w2tg fp32 [16][1024] (64KB; coalesced reads)
__global__ __launch_bounds__(256) void transpose_w2g(const float* __restrict__ in,
                                                     float* __restrict__ out) {
    int gid = blockIdx.x * 256 + threadIdx.x;   // 16384
    int c = gid >> 4, e = gid & 15;
    out[e * 1024 + c] = in[gid];
}

// Fused LN+GELU -> 16 logits -> softmax -> top4 -> renorm.
// ONE WAVE PER ROW: no barriers, no LDS, no atomics. Writes 4 weights +
// packed top-4 ids (u32). Scatter is done by compact_kernel.
__global__ __launch_bounds__(256) void ln_topk_wave(
    const float* __restrict__ g,
    const float* __restrict__ lng, const float* __restrict__ lnb,
    const float* __restrict__ w2t, const float* __restrict__ b2,
    float* __restrict__ wout, unsigned int* __restrict__ topk)
{
    const int tid = threadIdx.x;
    const int lane = tid & 63;
    const int b = (blockIdx.x << 2) + (tid >> 6);
    const float* row = g + (long)b * 1024;
    const int c0 = lane << 2;

    float4 xv[4];
    float s = 0.f, q = 0.f;
#pragma unroll
    for (int p = 0; p < 4; ++p) {
        float4 v = *(const float4*)(row + (p << 8) + c0);
        xv[p] = v;
        s += v.x + v.y + v.z + v.w;
        q += v.x * v.x + v.y * v.y + v.z * v.z + v.w * v.w;
    }
#pragma unroll
    for (int mk = 32; mk >= 1; mk >>= 1) {
        s += __shfl_xor(s, mk);
        q += __shfl_xor(q, mk);
    }
    const float mu = s * (1.0f / 1024.0f);
    const float var = q * (1.0f / 1024.0f) - mu * mu;
    const float rstd = rsqrtf(var + EPSN);

#pragma unroll
    for (int p = 0; p < 4; ++p) {
        float4 gv = *(const float4*)(lng + (p << 8) + c0);
        float4 bv = *(const float4*)(lnb + (p << 8) + c0);
        xv[p].x = gelu_f((xv[p].x - mu) * rstd * gv.x + bv.x);
        xv[p].y = gelu_f((xv[p].y - mu) * rstd * gv.y + bv.y);
        xv[p].z = gelu_f((xv[p].z - mu) * rstd * gv.z + bv.z);
        xv[p].w = gelu_f((xv[p].w - mu) * rstd * gv.w + bv.w);
    }

    // logits GEMV: a[e] += dot(xv[p], w2t[e][p*256 + lane*4 .. +3])
    float a[16];
#pragma unroll
    for (int i = 0; i < 16; ++i) a[i] = 0.f;
#pragma unroll
    for (int p = 0; p < 4; ++p) {
        const float4 x4 = xv[p];
        const float* wp = w2t + (p << 8) + c0;
#pragma unroll
        for (int e = 0; e < 16; ++e) {
            const float4 w = *(const float4*)(wp + (e << 10));
            a[e] = fmaf(x4.x, w.x, a[e]);
            a[e] = fmaf(x4.y, w.y, a[e]);
            a[e] = fmaf(x4.z, w.z, a[e]);
            a[e] = fmaf(x4.w, w.w, a[e]);
        }
    }
#pragma unroll
    for (int mk = 32; mk >= 1; mk >>= 1) {
#pragma unroll
        for (int i = 0; i < 16; ++i) a[i] += __shfl_xor(a[i], mk);
    }
#pragma unroll
    for (int i = 0; i < 16; ++i) a[i] += b2[i];

    // softmax (all lanes redundantly; uniform, no divergence)
    float m = a[0];
#pragma unroll
    for (int i = 1; i < 16; ++i) m = fmaxf(m, a[i]);
    float Z = 0.f;
#pragma unroll
    for (int i = 0; i < 16; ++i) { a[i] = expf(a[i] - m); Z += a[i]; }
    const float iZ = 1.0f / Z;
#pragma unroll
    for (int i = 0; i < 16; ++i) a[i] *= iZ;

    // top-4 with index tracking; static indexing only (rule #20)
    float tv0, tv1, tv2, tv3;
    int ti0, ti1, ti2, ti3;
#define PICK(TV, TI)                                                         \
    {   float bv = a[0]; int bi = 0;                                         \
        _Pragma("unroll")                                                    \
        for (int i = 1; i < 16; ++i) {                                       \
            bool t = a[i] > bv; bv = t ? a[i] : bv; bi = t ? i : bi;         \
        }                                                                    \
        TV = bv; TI = bi;                                                    \
        _Pragma("unroll")                                                    \
        for (int i = 0; i < 16; ++i) a[i] = (i == bi) ? -1.f : a[i];         \
    }
    PICK(tv0, ti0)
    PICK(tv1, ti1)
    PICK(tv2, ti2)
    PICK(tv3, ti3)
#undef PICK

    const float q1 = expf(tv1 - tv0);
    const float q2 = expf(tv2 - tv0);
    const float q3 = expf(tv3 - tv0);
    const float iZ2 = 1.0f / (1.0f + q1 + q2 + q3);
    if (lane < 4) {
        float wk = (lane == 0) ? 1.f : (lane == 1) ? q1 : (lane == 2) ? q2 : q3;
        wout[(b << 2) + lane] = wk * iZ2;
    }
    if (lane == 0)
        topk[b] = (unsigned)ti0 | ((unsigned)ti1 << 8) |
                  ((unsigned)ti2 << 16) | ((unsigned)ti3 << 24);
}

// Atomic-free scatter: one block per expert; ballot + LDS scan compaction
// over topk[4096]. Writes rows_[e<<12 ..] (row-ordered) and counts[e].
__global__ __launch_bounds__(256) void compact_kernel(const unsigned int* __restrict__ topk,
                                                      int* __restrict__ rows_,
                                                      int* __restrict__ counts) {
    const int e = blockIdx.x;           // 16
    const int tid = threadIdx.x;
    const int wid = tid >> 6, lane = tid & 63;
    __shared__ int wcnt[4];
    __shared__ int wbase[4];
    __shared__ int running;
    if (tid == 0) running = 0;
    __syncthreads();
    for (int c = 0; c < 16; ++c) {
        const int r = (c << 8) + tid;
        const unsigned int w = topk[r];
        int slot = -1;
        if (((w >> 0)  & 255u) == (unsigned)e) slot = (r << 2) | 0;
        if (((w >> 8)  & 255u) == (unsigned)e) slot = (r << 2) | 1;
        if (((w >> 16) & 255u) == (unsigned)e) slot = (r << 2) | 2;
        if (((w >> 24) & 255u) == (unsigned)e) slot = (r << 2) | 3;
        const unsigned long long m = __ballot(slot >= 0);
        if (lane == 0) wcnt[wid] = __popcll(m);
        __syncthreads();
        if (tid == 0) {
            int base = running;
#pragma unroll
            for (int i = 0; i < 4; ++i) { wbase[i] = base; base += wcnt[i]; }
            running = base;
        }
        __syncthreads();
        if (slot >= 0) {
            const int pref = __popcll(m & ((1ull << lane) - 1ull));
            rows_[(e << 12) + wbase[wid] + pref] = slot;
        }
        __syncthreads();
    }
    if (tid == 0) counts[e] = running;
}

// XCD-grouped worklist: wl[8][1024]; group g holds experts {g, g+8},
// entries (e<<16)|(mc<<4)|x for TM=128 tiles, mc-outer x-inner.
// Block bid -> group bid&7 (XCD round-robin heuristic), item bid>>3.
// Per-group worst case: 2 experts x 32 chunks x 8 = 512 entries <= 1024.
#define WLG 1024
__global__ __launch_bounds__(256) void build_wl_kernel(const int* __restrict__ counts,
                                                       int* __restrict__ wl) {
    int t = threadIdx.x;
    for (int i = t; i < 8 * WLG; i += 256) wl[i] = -1;
    __syncthreads();
    if (t < 8) {
        int* wg = wl + (t << 10);
        int idx = 0;
#pragma unroll
        for (int half = 0; half < 2; ++half) {
            int e = t + (half << 3);
            int nc = (counts[e] + 127) >> 7;
            for (int mc = 0; mc < nc; ++mc)
                for (int x = 0; x < 8; ++x)
                    wg[idx++] = (e << 16) | (mc << 4) | x;
        }
    }
}

// bf16 MFMA GEMM, m97 geometry: 128x128 tile, BK=64, 256 threads (4 waves),
// each wave owns a 64x64 quadrant = 4x4 16x16 fragments (64 acc VGPRs),
// 32 MFMA + 16 ds_read_b128 per wave per K-tile (MFMA:ds_read = 2.0).
// Serial 2-barrier loop (m97-proven; r12's 2-phase dbuf regressed).
// LDS: A [128][64] + B [128][64] bf16 = 32KB, k-chunk XOR swizzle
//   (chunk kc of row r at position kc^(r&7) -> 2-way conflicts, free).
// glds16 dest is lane-contiguous; swizzle applied via SOURCE pointer.
// WL: 1-D grid, XCD-grouped worklist decode. !WL: grid (x=m-chunk, y=e, z=n-chunk).
// OUTBF epilogue: BN+GELU -> bf16 via LDS in two 64-row halves -> 16B stores.
// PLAIN epilogue: bias only, fp32 out (bf16x3 gate GEMM).
template<int ASHIFT, bool GATHER, bool OUTBF, bool WL, bool PLAIN = false>
__global__ __launch_bounds__(256) void mfma_gemm(
    const unsigned short* __restrict__ A, int K,
    const unsigned short* __restrict__ Wt, long wstride,
    const float* __restrict__ bias,
    const float* __restrict__ bng, const float* __restrict__ bnb,
    const float* __restrict__ bnm, const float* __restrict__ bnv,
    int pstride,
    void* __restrict__ outv, int ldo,
    const int* __restrict__ rows_, const int* __restrict__ counts,
    const int* __restrict__ wl, int M)
{
    constexpr int TM = 128;
    int e, m0, n0;
    if constexpr (WL) {
        int w = wl[((blockIdx.x & 7) << 10) | (blockIdx.x >> 3)];
        if (w < 0) return;
        e = w >> 16;
        m0 = ((w >> 4) & 0xfff) << 7;
        n0 = (w & 15) << 7;
    } else {
        e = blockIdx.y;
        m0 = blockIdx.x * TM;
        n0 = blockIdx.z << 7;
    }
    const int cnt = GATHER ? counts[e] : M;

    constexpr int A_USH = 128 * 64;                     // 16KB
    constexpr int AB_USH = 2 * A_USH;                   // A+B = 32KB
    constexpr int OL_STRIDE = 136;                      // 272B rows (16B-aligned)
    __shared__ __align__(16) unsigned short smem[AB_USH];
    __shared__ int rid[TM];
    __shared__ int ain[TM];

    const int tid = threadIdx.x;
    if (tid < TM) {
        int i = m0 + tid;
        int pk, ai;
        if (GATHER) {
            if (i < cnt) { pk = rows_[(e << 12) + i]; ai = pk >> ASHIFT; }
            else { pk = -1; ai = 0; }
        } else { pk = i; ai = i; }
        rid[tid] = pk;
        ain[tid] = ai;
    }
    __syncthreads();

    const int wave = tid >> 6, lane = tid & 63;
    const int wm = (wave >> 1) << 6, wn = (wave & 1) << 6;   // 64x64 quadrant
    const int lrow = lane & 15, kch = lane >> 4;
    const int wb = wave << 9;          // per-wave base within each 2048-ush call

    // staging source map: row-in-32-block srow=tid>>3, dest chunk pos spos=tid&7,
    // source chunk = spos ^ (srow&7)  [XOR swizzle; row&7 == srow&7 since 32|p*32]
    const int srow = tid >> 3, spos = tid & 7;
    const int skc8 = (spos ^ (srow & 7)) << 3;

    const unsigned short* ap0 = A + (long)ain[srow] * K + skc8;
    const unsigned short* ap1 = A + (long)ain[32 + srow] * K + skc8;
    const unsigned short* ap2 = A + (long)ain[64 + srow] * K + skc8;
    const unsigned short* ap3 = A + (long)ain[96 + srow] * K + skc8;
    const unsigned short* Wte = Wt + (long)e * wstride;
    const unsigned short* bq0 = Wte + (long)(n0 + srow) * K + skc8;
    const unsigned short* bq1 = Wte + (long)(n0 + 32 + srow) * K + skc8;
    const unsigned short* bq2 = Wte + (long)(n0 + 64 + srow) * K + skc8;
    const unsigned short* bq3 = Wte + (long)(n0 + 96 + srow) * K + skc8;

    unsigned short* Als = smem;            // [128 rows][64 k]
    unsigned short* Bls = smem + A_USH;    // [128 rows][64 k]

    v4f acc[4][4] = {};

    const int nk = K >> 6;
    for (int it = 0; it < nk; ++it) {
        glds16(ap0, Als + wb);
        glds16(ap1, Als + 2048 + wb);
        glds16(ap2, Als + 4096 + wb);
        glds16(ap3, Als + 6144 + wb);
        glds16(bq0, Bls + wb);
        glds16(bq1, Bls + 2048 + wb);
        glds16(bq2, Bls + 4096 + wb);
        glds16(bq3, Bls + 6144 + wb);
        ap0 += 64; ap1 += 64; ap2 += 64; ap3 += 64;
        bq0 += 64; bq1 += 64; bq2 += 64; bq3 += 64;
        __syncthreads();

#pragma unroll
        for (int s = 0; s < 2; ++s) {
            const int kc = (s << 2) | kch;
            const int sw = (kc ^ (lrow & 7)) << 3;   // row&7 == lrow&7
            v8s av[4], bv[4];
#pragma unroll
            for (int f = 0; f < 4; ++f)
                av[f] = *(const v8s*)(Als + (wm + (f << 4) + lrow) * 64 + sw);
#pragma unroll
            for (int f = 0; f < 4; ++f)
                bv[f] = *(const v8s*)(Bls + (wn + (f << 4) + lrow) * 64 + sw);
#pragma unroll
            for (int fi = 0; fi < 4; ++fi)
#pragma unroll
                for (int fj = 0; fj < 4; ++fj)
                    acc[fi][fj] = __builtin_amdgcn_mfma_f32_16x16x32_bf16(
                        av[fi], bv[fj], acc[fi][fj], 0, 0, 0);
        }
        __syncthreads();
    }

    // epilogue: C/D layout col=lane&15, row=(lane>>4)*4+reg (per 16x16 frag)
    if constexpr (OUTBF) {
        unsigned short* Ols = smem;   // stage buffers dead after final barrier
#pragma unroll
        for (int h = 0; h < 2; ++h) {
            if ((wave >> 1) == h) {   // waves owning rows h*64..h*64+63
#pragma unroll
                for (int fj = 0; fj < 4; ++fj) {
                    const int c = wn + (fj << 4) + lrow;
                    const int pc = e * pstride + n0 + c;
                    const float bs = bias[pc];
                    const float sc = bng[pc] * rsqrtf(bnv[pc] + EPSN);
                    const float mn = bnm[pc], bb = bnb[pc];
#pragma unroll
                    for (int fi = 0; fi < 4; ++fi) {
#pragma unroll
                        for (int r = 0; r < 4; ++r) {
                            const int lrl = (fi << 4) + (kch << 2) + r;  // local row
                            float x = acc[fi][fj][r] + bs;
                            x = (x - mn) * sc + bb;
                            x = gelu_f(x);
                            Ols[lrl * OL_STRIDE + c] = f2bf(x);
                        }
                    }
                }
            }
            __syncthreads();
            const int rl = tid >> 4;
            const int c8 = (tid & 15) << 3;
#pragma unroll
            for (int p = 0; p < 4; ++p) {
                const int row = (p << 4) + rl;
                const int orow = rid[(h << 6) + row];
                if (orow >= 0) {
                    uint4 v = *(const uint4*)(Ols + row * OL_STRIDE + c8);
                    *(uint4*)((unsigned short*)outv + (long)orow * ldo + n0 + c8) = v;
                }
            }
            __syncthreads();
        }
    } else {
#pragma unroll
        for (int fj = 0; fj < 4; ++fj) {
            const int c = n0 + wn + (fj << 4) + lrow;
            const int pc = e * pstride + c;
            const float bs = bias[pc];
            float sc = 1.f, mn = 0.f, bb = 0.f;
            if constexpr (!PLAIN) {
                sc = bng[pc] * rsqrtf(bnv[pc] + EPSN);
                mn = bnm[pc]; bb = bnb[pc];
            }
#pragma unroll
            for (int fi = 0; fi < 4; ++fi) {
#pragma unroll
                for (int r = 0; r < 4; ++r) {
                    const int lr = wm + (fi << 4) + (kch << 2) + r;
                    const int orow = rid[lr];
                    if (orow < 0) continue;
                    float x = acc[fi][fj][r] + bs;
                    if constexpr (!PLAIN) {
                        x = (x - mn) * sc + bb;
                        x = gelu_f(x);
                    }
                    ((float*)outv)[(long)orow * ldo + c] = x;
                }
            }
        }
    }
}

// weighted top-4 combine, bf16 in -> bf16 out
__global__ __launch_bounds__(256) void combine_bf_kernel(const ushort4* __restrict__ h2b,
                                                         const float* __restrict__ w,
                                                         ushort4* __restrict__ fusedb) {
    int gid = blockIdx.x * 256 + threadIdx.x;  // 4096*256
    int b = gid >> 8, c = gid & 255;
    float a0 = 0.f, a1 = 0.f, a2 = 0.f, a3 = 0.f;
#pragma unroll
    for (int k = 0; k < 4; ++k) {
        float wk = w[b * 4 + k];
        ushort4 v = h2b[(long)(b * 4 + k) * 256 + c];
        a0 += wk * bf2f(v.x); a1 += wk * bf2f(v.y);
        a2 += wk * bf2f(v.z); a3 += wk * bf2f(v.w);
    }
    ushort4 o;
    o.x = f2bf(a0); o.y = f2bf(a1); o.z = f2bf(a2); o.w = f2bf(a3);
    fusedb[gid] = o;
}

__global__ __launch_bounds__(256) void fin2_kernel(const float* __restrict__ o,
                                                   const float* __restrict__ w2,
                                                   const float* __restrict__ b2,
                                                   float* __restrict__ out) {
    __shared__ float ws[512 * 20];
    int tid = threadIdx.x;
    for (int i = tid; i < 512 * 20; i += 256) ws[i] = w2[i];
    __syncthreads();
    int r = blockIdx.x * 64 + (tid >> 2);
    int c0 = (tid & 3) * 5;
    float acc[5];
#pragma unroll
    for (int j = 0; j < 5; ++j) acc[j] = b2[c0 + j];
    const float* orow = o + (long)r * 512;
    for (int i = 0; i < 512; ++i) {
        float v = orow[i];
#pragma unroll
        for (int j = 0; j < 5; ++j) acc[j] += v * ws[i * 20 + c0 + j];
    }
#pragma unroll
    for (int j = 0; j < 5; ++j) out[r * 20 + c0 + j] = acc[j];
}

extern "C" void kernel_launch(void* const* d_in, const int* in_sizes, int n_in,
                              void* d_out, int out_size, void* d_ws, size_t ws_size,
                              hipStream_t stream) {
    const float* wifi    = (const float*)d_in[0];
    const float* rfid    = (const float*)d_in[1];
    const float* gate_w1 = (const float*)d_in[2];
    const float* gate_b1 = (const float*)d_in[3];
    const float* gln_g   = (const float*)d_in[4];
    const float* gln_b   = (const float*)d_in[5];
    const float* gate_w2 = (const float*)d_in[6];
    const float* gate_b2 = (const float*)d_in[7];
    const float* exp_w1  = (const float*)d_in[8];
    const float* exp_b1  = (const float*)d_in[9];
    const float* bn1g    = (const float*)d_in[10];
    const float* bn1b    = (const float*)d_in[11];
    const float* bn1m    = (const float*)d_in[12];
    const float* bn1v    = (const float*)d_in[13];
    const float* exp_w2  = (const float*)d_in[14];
    const float* exp_b2  = (const float*)d_in[15];
    const float* bn2g    = (const float*)d_in[16];
    const float* bn2b    = (const float*)d_in[17];
    const float* bn2m    = (const float*)d_in[18];
    const float* bn2v    = (const float*)d_in[19];
    const float* fin_w1  = (const float*)d_in[20];
    const float* fin_b1  = (const float*)d_in[21];
    const float* fbng    = (const float*)d_in[22];
    const float* fbnb    = (const float*)d_in[23];
    const float* fbnm    = (const float*)d_in[24];
    const float* fbnv    = (const float*)d_in[25];
    const float* fin_w2  = (const float*)d_in[26];
    const float* fin_b2  = (const float*)d_in[27];
    float* out = (float*)d_out;

    const size_t MBy = 1u << 20;
    char* W = (char*)d_ws;
    float*          combined = (float*)         (W + 0);
    unsigned short* cbf      = (unsigned short*)(W + 8 * MBy);
    unsigned short* w1t      = (unsigned short*)(W + 12 * MBy);
    unsigned short* fusedb   = (unsigned short*)(W + 12 * MBy);   // after w1t dead
    float*          obuf     = (float*)         (W + 20 * MBy);   // after w1t dead
    unsigned short* w2t      = (unsigned short*)(W + 29 * MBy);
    float*          wq       = (float*)         (W + 61 * MBy);
    int*            rows     = (int*)           (W + 61 * MBy + (1 << 16));
    int*            counts   = (int*)           (W + 61 * MBy + (1 << 16) + (1 << 18));
    int*            wl       = (int*)           (W + 61 * MBy + (1 << 16) + (1 << 18) + 256);
    unsigned int*   topk     = (unsigned int*)  (W + 61 * MBy + (6 << 16));   // 16KB
    float*          w2tg     = (float*)         (W + 62 * MBy);
    unsigned short* fw1t     = (unsigned short*)(W + 63 * MBy);
    unsigned short* h1bf     = (unsigned short*)(W + 65 * MBy);
    unsigned short* cbf3     = (unsigned short*)(W + 65 * MBy);   // dead before h1bf written
    unsigned short* w1t3     = (unsigned short*)(W + 77 * MBy);   // dead before h1bf written
    float*          gbuf     = (float*)         (W + 99 * MBy);
    unsigned short* h2b      = (unsigned short*)(W + 99 * MBy);   // after gbuf dead

    concat_kernel<<<2048, 256, 0, stream>>>((const float4*)wifi, (const float4*)rfid,
                                            (float4*)combined, (ushort4*)cbf,
                                            (ushort4*)cbf3);

    // weight transposes fp32 [K][N] -> bf16 [N][K]
    transpose_f2b<<<dim3(16, 8, 16), 256, 0, stream>>>(exp_w1, w1t, 512, 1024);
    transpose_f2b<<<dim3(16, 16, 16), 256, 0, stream>>>(exp_w2, w2t, 1024, 1024);
    transpose_f2b<<<dim3(8, 16, 1), 256, 0, stream>>>(fin_w1, fw1t, 1024, 512);
    // gate_w1 -> bf16x3 [1024][1536] rows [hi | hi | lo]
    transpose_f2b_hilo<<<dim3(16, 8, 1), 256, 0, stream>>>(gate_w1, w1t3, 512, 1024);
    // gate_w2 [1024][16] -> [16][1024] fp32 for coalesced GEMV
    transpose_w2g<<<64, 256, 0, stream>>>(gate_w2, w2tg);

    // gate GEMM1 (dense, bf16x3 split-precision MFMA, K'=1536):
    //   cbf3 [hi|lo|hi] x w1t3 [hi|hi|lo] = Ahi.Whi + Alo.Whi + Ahi.Wlo
    // PLAIN epilogue: +bias, fp32 out -> gbuf. Grid: x=m-chunk drives XCD.
    mfma_gemm<0, false, false, false, true><<<dim3(32, 1, 8), 256, 0, stream>>>(
        cbf3, 1536, w1t3, 0, gate_b1,
        nullptr, nullptr, nullptr, nullptr, 0,
        gbuf, 1024, nullptr, nullptr, nullptr, 4096);

    // wave-per-row LN/GELU/logits/softmax/top4 (no barriers, no LDS, no atomics)
    ln_topk_wave<<<1024, 256, 0, stream>>>(gbuf, gln_g, gln_b, w2tg, gate_b2,
                                           wq, topk);
    // atomic-free scatter: rows/counts per expert
    compact_kernel<<<16, 256, 0, stream>>>(topk, rows, counts);
    build_wl_kernel<<<1, 256, 0, stream>>>(counts, wl);

    // expert GEMM1 (XCD worklist, bf16 MFMA, K=512, TM=128): cbf -> h1bf[slot]
    // grid 4096 covers per-group worst case 512 entries (bid>>3 < 1024)
    mfma_gemm<2, true, true, true><<<dim3(4096, 1, 1), 256, 0, stream>>>(
        cbf, 512, w1t, (long)512 * 1024, exp_b1,
        bn1g, bn1b, bn1m, bn1v, 1024,
        h1bf, 1024, rows, counts, wl, 4096);

    // expert GEMM2 (XCD worklist, bf16 MFMA, K=1024, TM=128): h1bf -> h2b[slot]
    mfma_gemm<0, true, true, true><<<dim3(4096, 1, 1), 256, 0, stream>>>(
        h1bf, 1024, w2t, (long)1024 * 1024, exp_b2,
        bn2g, bn2b, bn2m, bn2v, 1024,
        h2b, 1024, rows, counts, wl, 4096);

    combine_bf_kernel<<<4096, 256, 0, stream>>>((const ushort4*)h2b, wq, (ushort4*)fusedb);

    // final GEMM1 (dense, bf16 MFMA, TM=128): fusedb -> obuf fp32, BN+GELU
    mfma_gemm<0, false, false, false><<<dim3(32, 1, 4), 256, 0, stream>>>(
        fusedb, 1024, fw1t, 0, fin_b1,
        fbng, fbnb, fbnm, fbnv, 0,
        obuf, 512, nullptr, nullptr, nullptr, 4096);

    fin2_kernel<<<64, 256, 0, stream>>>(obuf, fin_w2, fin_b2, out);
}

// Round 7
// 451.939 us; speedup vs baseline: 1.6380x; 1.6380x over previous
//
#include <hip/hip_runtime.h>

// MoE_77644418777543 — round 14.
// r13 post-mortem: 128x128 tile REGRESSED 2.5x (71->177us eGEMM). Mechanism:
// MfmaUtil x dur conserved (same MFMA work, pure stall scaling); VGPR 88 +
// 64 AGPR -> 3 waves/SIMD cap. Law fitting r11/r12/r13: achieved occupancy
// ~= 0.45 x static wave limit, and perf ~ resident waves (latency-bound).
// This round: MAXIMIZE the static wave limit. 64x64 tile, 4 waves x 32x32
// (acc[2][2]=16 AGPR, ~56 regs -> 9 waves/SIMD), LDS 16KB (9 blocks/CU)
// -> static cap = 32 waves/CU (hardware max; r11 was 24, r13 was 12).
// Inner loop = strict subset of r11's proven code. Worklist TN=64 (x<16),
// WLG=2048, grid 16384. Dense grids n0 = z<<6.
//
// Workspace (MB = 2^20), aliased by liveness:
//   0-8M    combined fp32            (gate concat; then dead)
//   8-12M   cbf bf16                 (dead after expert GEMM1)
//   12-28M  w1t bf16 [16][1024][512] (dead after GEMM1) / fusedb@12M, obuf@20M after
//   29-61M  w2t bf16 [16][1024][1024](dead after GEMM2)
//   61M     wq / rows / counts / wl[8][2048] / topk u32[4096]@+0x70000
//   62M     w2tg fp32 [16][1024] (gate w2 transposed, 64KB)
//   63-64M  fw1t bf16 [512][1024]
//   65-97M  h1bf bf16 [16384][1024]  (written by expert GEMM1)
//     65-77M  cbf3 bf16 [4096][1536]  (dead after gate MFMA -> safe alias)
//     77-80M  w1t3 bf16 [1024][1536]  (dead after gate MFMA -> safe alias)
//   99-131M gbuf fp32 (dead after ln_topk) then h2b bf16 [16384][1024]

#define EPSN 1e-5f

typedef __attribute__((ext_vector_type(8))) short v8s;   // 8 bf16 (4 VGPRs)
typedef __attribute__((ext_vector_type(4))) float v4f;   // 4 fp32 acc

typedef const unsigned int __attribute__((address_space(1)))* gas_u32;
typedef unsigned int __attribute__((address_space(3)))* las_u32;

__device__ __forceinline__ void glds16(const void* g, const void* l) {
    __builtin_amdgcn_global_load_lds((gas_u32)(uintptr_t)g, (las_u32)(uintptr_t)l, 16, 0, 0);
}

__device__ __forceinline__ float gelu_f(float x) {
    return 0.5f * x * (1.0f + erff(x * 0.70710678118654752440f));
}
__device__ __forceinline__ unsigned short f2bf(float x) {
    unsigned int u = __float_as_uint(x);
    u += 0x7fffu + ((u >> 16) & 1u);
    return (unsigned short)(u >> 16);
}
__device__ __forceinline__ float bf2f(unsigned short u) {
    return __uint_as_float(((unsigned int)u) << 16);
}

// concat wifi|rfid -> combined fp32; bf16 copy for expert GEMM1; and
// bf16x3 row [hi(512) | lo(512) | hi(512)] for the split-precision gate GEMM.
__global__ __launch_bounds__(256) void concat_kernel(const float4* __restrict__ wifi,
                                                     const float4* __restrict__ rfid,
                                                     float4* __restrict__ comb,
                                                     ushort4* __restrict__ cbf,
                                                     ushort4* __restrict__ cbf3) {
    int gid = blockIdx.x * 256 + threadIdx.x;   // 4096 * 128
    int b = gid >> 7, c = gid & 127;
    float4 v = (c < 64) ? wifi[b * 64 + c] : rfid[b * 64 + (c - 64)];
    comb[gid] = v;
    ushort4 hi, lo;
    hi.x = f2bf(v.x); hi.y = f2bf(v.y); hi.z = f2bf(v.z); hi.w = f2bf(v.w);
    lo.x = f2bf(v.x - bf2f(hi.x));
    lo.y = f2bf(v.y - bf2f(hi.y));
    lo.z = f2bf(v.z - bf2f(hi.z));
    lo.w = f2bf(v.w - bf2f(hi.w));
    cbf[gid] = hi;
    const long r3 = (long)b * 384 + c;          // 1536 ush row = 384 ushort4
    cbf3[r3]       = hi;
    cbf3[r3 + 128] = lo;
    cbf3[r3 + 256] = hi;
}

// in: per-expert [K][N] fp32 -> out: per-expert [N][K] bf16 (transpose+convert)
__global__ __launch_bounds__(256) void transpose_f2b(const float* __restrict__ in,
                                                     unsigned short* __restrict__ out,
                                                     int K, int N) {
    __shared__ float t[64][65];
    int e = blockIdx.z;
    int n0 = blockIdx.x << 6, k0 = blockIdx.y << 6;
    const float* ie = in + (long)e * K * N;
    unsigned short* oe = out + (long)e * N * K;
    int tid = threadIdx.x;
    int rr = tid >> 4, cc = (tid & 15) << 2;
#pragma unroll
    for (int p = 0; p < 4; ++p) {
        int k = (p << 4) + rr;
        float4 v = *(const float4*)(ie + (long)(k0 + k) * N + n0 + cc);
        t[k][cc + 0] = v.x; t[k][cc + 1] = v.y; t[k][cc + 2] = v.z; t[k][cc + 3] = v.w;
    }
    __syncthreads();
    int n = tid >> 2, kq = (tid & 3) << 4;
    unsigned short u[16];
#pragma unroll
    for (int j = 0; j < 16; ++j) u[j] = f2bf(t[kq + j][n]);
    uint4* dst = (uint4*)(oe + (long)(n0 + n) * K + k0 + kq);
    dst[0] = ((const uint4*)u)[0];
    dst[1] = ((const uint4*)u)[1];
}

// gate_w1 [K=512][N=1024] fp32 -> w1t3 [N][3K=1536] bf16, rows [hi | hi | lo]
__global__ __launch_bounds__(256) void transpose_f2b_hilo(const float* __restrict__ in,
                                                          unsigned short* __restrict__ out,
                                                          int K, int N) {
    __shared__ float t[64][65];
    int n0 = blockIdx.x << 6, k0 = blockIdx.y << 6;
    int tid = threadIdx.x;
    int rr = tid >> 4, cc = (tid & 15) << 2;
#pragma unroll
    for (int p = 0; p < 4; ++p) {
        int k = (p << 4) + rr;
        float4 v = *(const float4*)(in + (long)(k0 + k) * N + n0 + cc);
        t[k][cc + 0] = v.x; t[k][cc + 1] = v.y; t[k][cc + 2] = v.z; t[k][cc + 3] = v.w;
    }
    __syncthreads();
    int n = tid >> 2, kq = (tid & 3) << 4;
    unsigned short uh[16], ul[16];
#pragma unroll
    for (int j = 0; j < 16; ++j) {
        float x = t[kq + j][n];
        unsigned short h = f2bf(x);
        uh[j] = h;
        ul[j] = f2bf(x - bf2f(h));
    }
    unsigned short* dh = out + (long)(n0 + n) * (3 * K) + k0 + kq;
    ((uint4*)dh)[0]           = ((const uint4*)uh)[0];
    ((uint4*)dh)[1]           = ((const uint4*)uh)[1];
    ((uint4*)(dh + K))[0]     = ((const uint4*)uh)[0];
    ((uint4*)(dh + K))[1]     = ((const uint4*)uh)[1];
    ((uint4*)(dh + 2 * K))[0] = ((const uint4*)ul)[0];
    ((uint4*)(dh + 2 * K))[1] = ((const uint4*)ul)[1];
}

// gate_w2 fp32 [1024][16] -> w2tg fp32 [16][1024] (64KB; coalesced reads)
__global__ __launch_bounds__(256) void transpose_w2g(const float* __restrict__ in,
                                                     float* __restrict__ out) {
    int gid = blockIdx.x * 256 + threadIdx.x;   // 16384
    int c = gid >> 4, e = gid & 15;
    out[e * 1024 + c] = in[gid];
}

// Fused LN+GELU -> 16 logits -> softmax -> top4 -> renorm.
// ONE WAVE PER ROW: no barriers, no LDS, no atomics. Writes 4 weights +
// packed top-4 ids (u32). Scatter is done by compact_kernel.
__global__ __launch_bounds__(256) void ln_topk_wave(
    const float* __restrict__ g,
    const float* __restrict__ lng, const float* __restrict__ lnb,
    const float* __restrict__ w2t, const float* __restrict__ b2,
    float* __restrict__ wout, unsigned int* __restrict__ topk)
{
    const int tid = threadIdx.x;
    const int lane = tid & 63;
    const int b = (blockIdx.x << 2) + (tid >> 6);
    const float* row = g + (long)b * 1024;
    const int c0 = lane << 2;

    float4 xv[4];
    float s = 0.f, q = 0.f;
#pragma unroll
    for (int p = 0; p < 4; ++p) {
        float4 v = *(const float4*)(row + (p << 8) + c0);
        xv[p] = v;
        s += v.x + v.y + v.z + v.w;
        q += v.x * v.x + v.y * v.y + v.z * v.z + v.w * v.w;
    }
#pragma unroll
    for (int mk = 32; mk >= 1; mk >>= 1) {
        s += __shfl_xor(s, mk);
        q += __shfl_xor(q, mk);
    }
    const float mu = s * (1.0f / 1024.0f);
    const float var = q * (1.0f / 1024.0f) - mu * mu;
    const float rstd = rsqrtf(var + EPSN);

#pragma unroll
    for (int p = 0; p < 4; ++p) {
        float4 gv = *(const float4*)(lng + (p << 8) + c0);
        float4 bv = *(const float4*)(lnb + (p << 8) + c0);
        xv[p].x = gelu_f((xv[p].x - mu) * rstd * gv.x + bv.x);
        xv[p].y = gelu_f((xv[p].y - mu) * rstd * gv.y + bv.y);
        xv[p].z = gelu_f((xv[p].z - mu) * rstd * gv.z + bv.z);
        xv[p].w = gelu_f((xv[p].w - mu) * rstd * gv.w + bv.w);
    }

    // logits GEMV: a[e] += dot(xv[p], w2t[e][p*256 + lane*4 .. +3])
    float a[16];
#pragma unroll
    for (int i = 0; i < 16; ++i) a[i] = 0.f;
#pragma unroll
    for (int p = 0; p < 4; ++p) {
        const float4 x4 = xv[p];
        const float* wp = w2t + (p << 8) + c0;
#pragma unroll
        for (int e = 0; e < 16; ++e) {
            const float4 w = *(const float4*)(wp + (e << 10));
            a[e] = fmaf(x4.x, w.x, a[e]);
            a[e] = fmaf(x4.y, w.y, a[e]);
            a[e] = fmaf(x4.z, w.z, a[e]);
            a[e] = fmaf(x4.w, w.w, a[e]);
        }
    }
#pragma unroll
    for (int mk = 32; mk >= 1; mk >>= 1) {
#pragma unroll
        for (int i = 0; i < 16; ++i) a[i] += __shfl_xor(a[i], mk);
    }
#pragma unroll
    for (int i = 0; i < 16; ++i) a[i] += b2[i];

    // softmax (all lanes redundantly; uniform, no divergence)
    float m = a[0];
#pragma unroll
    for (int i = 1; i < 16; ++i) m = fmaxf(m, a[i]);
    float Z = 0.f;
#pragma unroll
    for (int i = 0; i < 16; ++i) { a[i] = expf(a[i] - m); Z += a[i]; }
    const float iZ = 1.0f / Z;
#pragma unroll
    for (int i = 0; i < 16; ++i) a[i] *= iZ;

    // top-4 with index tracking; static indexing only (rule #20)
    float tv0, tv1, tv2, tv3;
    int ti0, ti1, ti2, ti3;
#define PICK(TV, TI)                                                         \
    {   float bv = a[0]; int bi = 0;                                         \
        _Pragma("unroll")                                                    \
        for (int i = 1; i < 16; ++i) {                                       \
            bool t = a[i] > bv; bv = t ? a[i] : bv; bi = t ? i : bi;         \
        }                                                                    \
        TV = bv; TI = bi;                                                    \
        _Pragma("unroll")                                                    \
        for (int i = 0; i < 16; ++i) a[i] = (i == bi) ? -1.f : a[i];         \
    }
    PICK(tv0, ti0)
    PICK(tv1, ti1)
    PICK(tv2, ti2)
    PICK(tv3, ti3)
#undef PICK

    const float q1 = expf(tv1 - tv0);
    const float q2 = expf(tv2 - tv0);
    const float q3 = expf(tv3 - tv0);
    const float iZ2 = 1.0f / (1.0f + q1 + q2 + q3);
    if (lane < 4) {
        float wk = (lane == 0) ? 1.f : (lane == 1) ? q1 : (lane == 2) ? q2 : q3;
        wout[(b << 2) + lane] = wk * iZ2;
    }
    if (lane == 0)
        topk[b] = (unsigned)ti0 | ((unsigned)ti1 << 8) |
                  ((unsigned)ti2 << 16) | ((unsigned)ti3 << 24);
}

// Atomic-free scatter: one block per expert; ballot + LDS scan compaction
// over topk[4096]. Writes rows_[e<<12 ..] (row-ordered) and counts[e].
__global__ __launch_bounds__(256) void compact_kernel(const unsigned int* __restrict__ topk,
                                                      int* __restrict__ rows_,
                                                      int* __restrict__ counts) {
    const int e = blockIdx.x;           // 16
    const int tid = threadIdx.x;
    const int wid = tid >> 6, lane = tid & 63;
    __shared__ int wcnt[4];
    __shared__ int wbase[4];
    __shared__ int running;
    if (tid == 0) running = 0;
    __syncthreads();
    for (int c = 0; c < 16; ++c) {
        const int r = (c << 8) + tid;
        const unsigned int w = topk[r];
        int slot = -1;
        if (((w >> 0)  & 255u) == (unsigned)e) slot = (r << 2) | 0;
        if (((w >> 8)  & 255u) == (unsigned)e) slot = (r << 2) | 1;
        if (((w >> 16) & 255u) == (unsigned)e) slot = (r << 2) | 2;
        if (((w >> 24) & 255u) == (unsigned)e) slot = (r << 2) | 3;
        const unsigned long long m = __ballot(slot >= 0);
        if (lane == 0) wcnt[wid] = __popcll(m);
        __syncthreads();
        if (tid == 0) {
            int base = running;
#pragma unroll
            for (int i = 0; i < 4; ++i) { wbase[i] = base; base += wcnt[i]; }
            running = base;
        }
        __syncthreads();
        if (slot >= 0) {
            const int pref = __popcll(m & ((1ull << lane) - 1ull));
            rows_[(e << 12) + wbase[wid] + pref] = slot;
        }
        __syncthreads();
    }
    if (tid == 0) counts[e] = running;
}

// XCD-grouped worklist: wl[8][2048]; group g holds experts {g, g+8},
// entries (e<<16)|(mc<<4)|x for TM=64/TN=64 tiles, mc-outer x-inner (16
// consecutive entries share one A-tile -> L2-resident on their XCD).
// Block bid -> group bid&7, item bid>>3. Per-group worst case:
// 2 experts x 64 chunks x 16 = 2048 entries (cnt[e] <= 4096).
#define WLG 2048
__global__ __launch_bounds__(256) void build_wl_kernel(const int* __restrict__ counts,
                                                       int* __restrict__ wl) {
    int t = threadIdx.x;
    for (int i = t; i < 8 * WLG; i += 256) wl[i] = -1;
    __syncthreads();
    if (t < 8) {
        int* wg = wl + (t << 11);
        int idx = 0;
#pragma unroll
        for (int half = 0; half < 2; ++half) {
            int e = t + (half << 3);
            int nc = (counts[e] + 63) >> 6;
            for (int mc = 0; mc < nc; ++mc)
                for (int x = 0; x < 16; ++x)
                    wg[idx++] = (e << 16) | (mc << 4) | x;
        }
    }
}

// bf16 MFMA GEMM: 64x64 tile, BK=64, 256 threads (4 waves, 2x2 grid of
// 32x32 quadrants), acc[2][2] (16 AGPR), ~56 total regs -> 9 waves/SIMD;
// LDS A[64][64]+B[64][64] = 16KB -> 9 blocks/CU; static cap = 32 waves/CU
// (hardware max). Serial 2-barrier loop (proven structure), 8 MFMA +
// 8 ds_read_b128 + 4 glds16 per wave per K-iter. k-chunk XOR swizzle
// (kc^(row&7) -> 2-way, free); swizzle via SOURCE pointer for glds16.
// WL: 1-D grid, XCD-grouped decode. !WL: grid (x=m-chunk, y=e, z=n-chunk).
// OUTBF epilogue: BN+GELU -> bf16 LDS tile [64][72] -> 16B row stores.
// PLAIN epilogue: bias only, fp32 out (bf16x3 gate GEMM).
template<int ASHIFT, bool GATHER, bool OUTBF, bool WL, bool PLAIN = false>
__global__ __launch_bounds__(256) void mfma_gemm(
    const unsigned short* __restrict__ A, int K,
    const unsigned short* __restrict__ Wt, long wstride,
    const float* __restrict__ bias,
    const float* __restrict__ bng, const float* __restrict__ bnb,
    const float* __restrict__ bnm, const float* __restrict__ bnv,
    int pstride,
    void* __restrict__ outv, int ldo,
    const int* __restrict__ rows_, const int* __restrict__ counts,
    const int* __restrict__ wl, int M)
{
    constexpr int TM = 64;
    int e, m0, n0;
    if constexpr (WL) {
        int w = wl[((blockIdx.x & 7) << 11) | (blockIdx.x >> 3)];
        if (w < 0) return;
        e = w >> 16;
        m0 = ((w >> 4) & 0xfff) << 6;
        n0 = (w & 15) << 6;
    } else {
        e = blockIdx.y;
        m0 = blockIdx.x * TM;
        n0 = blockIdx.z << 6;
    }
    const int cnt = GATHER ? counts[e] : M;

    constexpr int A_USH = 64 * 64;                      // 8KB
    constexpr int AB_USH = 2 * A_USH;                   // A+B = 16KB
    constexpr int OL_STRIDE = 72;                       // 144B rows (16B-aligned)
    __shared__ __align__(16) unsigned short smem[AB_USH];   // epilogue reuses (64*72<=8192)
    __shared__ int rid[TM];
    __shared__ int ain[TM];

    const int tid = threadIdx.x;
    if (tid < TM) {
        int i = m0 + tid;
        int pk, ai;
        if (GATHER) {
            if (i < cnt) { pk = rows_[(e << 12) + i]; ai = pk >> ASHIFT; }
            else { pk = -1; ai = 0; }
        } else { pk = i; ai = i; }
        rid[tid] = pk;
        ain[tid] = ai;
    }
    __syncthreads();

    const int wave = tid >> 6, lane = tid & 63;
    const int wm = (wave >> 1) << 5, wn = (wave & 1) << 5;   // 2x2 waves: 32x32 each
    const int lrow = lane & 15, kch = lane >> 4;
    const int wb = wave << 9;          // per-wave base within each 2048-ush call

    // staging source map: row srow=tid>>3 (0..31), dest chunk pos spos=tid&7,
    // source chunk = spos ^ (srow&7)   [XOR swizzle]
    const int srow = tid >> 3, spos = tid & 7;
    const int skc8 = (spos ^ (srow & 7)) << 3;

    const unsigned short* ap0 = A + (long)ain[srow] * K + skc8;
    const unsigned short* ap1 = A + (long)ain[32 + srow] * K + skc8;
    const unsigned short* Wte = Wt + (long)e * wstride;
    const unsigned short* bq0 = Wte + (long)(n0 + srow) * K + skc8;
    const unsigned short* bq1 = Wte + (long)(n0 + 32 + srow) * K + skc8;

    unsigned short* Als = smem;            // [64 rows][64 k]
    unsigned short* Bls = smem + A_USH;    // [64 rows][64 k]

    v4f acc[2][2] = {};

    const int nk = K >> 6;
    for (int it = 0; it < nk; ++it) {
        glds16(ap0, Als + wb);
        glds16(ap1, Als + 2048 + wb);
        glds16(bq0, Bls + wb);
        glds16(bq1, Bls + 2048 + wb);
        ap0 += 64; ap1 += 64; bq0 += 64; bq1 += 64;
        __syncthreads();

#pragma unroll
        for (int s = 0; s < 2; ++s) {
            const int kc = (s << 2) | kch;
            const int sw = (kc ^ (lrow & 7)) << 3;   // row&7 == lrow&7
            v8s av[2], bv[2];
            av[0] = *(const v8s*)(Als + (wm + lrow) * 64 + sw);
            av[1] = *(const v8s*)(Als + (wm + 16 + lrow) * 64 + sw);
            bv[0] = *(const v8s*)(Bls + (wn + lrow) * 64 + sw);
            bv[1] = *(const v8s*)(Bls + (wn + 16 + lrow) * 64 + sw);
            acc[0][0] = __builtin_amdgcn_mfma_f32_16x16x32_bf16(av[0], bv[0], acc[0][0], 0, 0, 0);
            acc[0][1] = __builtin_amdgcn_mfma_f32_16x16x32_bf16(av[0], bv[1], acc[0][1], 0, 0, 0);
            acc[1][0] = __builtin_amdgcn_mfma_f32_16x16x32_bf16(av[1], bv[0], acc[1][0], 0, 0, 0);
            acc[1][1] = __builtin_amdgcn_mfma_f32_16x16x32_bf16(av[1], bv[1], acc[1][1], 0, 0, 0);
        }
        __syncthreads();
    }

    // epilogue: C/D layout col=lane&15, row=(lane>>4)*4+reg (per 16x16 frag)
    if constexpr (OUTBF) {
        unsigned short* Ols = smem;   // stage buffers dead after final barrier
#pragma unroll
        for (int fj = 0; fj < 2; ++fj) {
            const int c = wn + (fj << 4) + lrow;
            const int pc = e * pstride + n0 + c;
            const float bs = bias[pc];
            const float sc = bng[pc] * rsqrtf(bnv[pc] + EPSN);
            const float mn = bnm[pc], bb = bnb[pc];
#pragma unroll
            for (int fi = 0; fi < 2; ++fi) {
#pragma unroll
                for (int r = 0; r < 4; ++r) {
                    const int lr = wm + (fi << 4) + (kch << 2) + r;
                    float x = acc[fi][fj][r] + bs;
                    x = (x - mn) * sc + bb;
                    x = gelu_f(x);
                    Ols[lr * OL_STRIDE + c] = f2bf(x);
                }
            }
        }
        __syncthreads();
        const int rl = tid >> 3;          // 0..31
        const int c8 = (tid & 7) << 3;    // 0..56
#pragma unroll
        for (int p = 0; p < 2; ++p) {
            const int row = (p << 5) + rl;
            const int orow = rid[row];
            if (orow >= 0) {
                uint4 v = *(const uint4*)(Ols + row * OL_STRIDE + c8);
                *(uint4*)((unsigned short*)outv + (long)orow * ldo + n0 + c8) = v;
            }
        }
    } else {
#pragma unroll
        for (int fj = 0; fj < 2; ++fj) {
            const int c = n0 + wn + (fj << 4) + lrow;
            const int pc = e * pstride + c;
            const float bs = bias[pc];
            float sc = 1.f, mn = 0.f, bb = 0.f;
            if constexpr (!PLAIN) {
                sc = bng[pc] * rsqrtf(bnv[pc] + EPSN);
                mn = bnm[pc]; bb = bnb[pc];
            }
#pragma unroll
            for (int fi = 0; fi < 2; ++fi) {
#pragma unroll
                for (int r = 0; r < 4; ++r) {
                    const int lr = wm + (fi << 4) + (kch << 2) + r;
                    const int orow = rid[lr];
                    if (orow < 0) continue;
                    float x = acc[fi][fj][r] + bs;
                    if constexpr (!PLAIN) {
                        x = (x - mn) * sc + bb;
                        x = gelu_f(x);
                    }
                    ((float*)outv)[(long)orow * ldo + c] = x;
                }
            }
        }
    }
}

// weighted top-4 combine, bf16 in -> bf16 out
__global__ __launch_bounds__(256) void combine_bf_kernel(const ushort4* __restrict__ h2b,
                                                         const float* __restrict__ w,
                                                         ushort4* __restrict__ fusedb) {
    int gid = blockIdx.x * 256 + threadIdx.x;  // 4096*256
    int b = gid >> 8, c = gid & 255;
    float a0 = 0.f, a1 = 0.f, a2 = 0.f, a3 = 0.f;
#pragma unroll
    for (int k = 0; k < 4; ++k) {
        float wk = w[b * 4 + k];
        ushort4 v = h2b[(long)(b * 4 + k) * 256 + c];
        a0 += wk * bf2f(v.x); a1 += wk * bf2f(v.y);
        a2 += wk * bf2f(v.z); a3 += wk * bf2f(v.w);
    }
    ushort4 o;
    o.x = f2bf(a0); o.y = f2bf(a1); o.z = f2bf(a2); o.w = f2bf(a3);
    fusedb[gid] = o;
}

__global__ __launch_bounds__(256) void fin2_kernel(const float* __restrict__ o,
                                                   const float* __restrict__ w2,
                                                   const float* __restrict__ b2,
                                                   float* __restrict__ out) {
    __shared__ float ws[512 * 20];
    int tid = threadIdx.x;
    for (int i = tid; i < 512 * 20; i += 256) ws[i] = w2[i];
    __syncthreads();
    int r = blockIdx.x * 64 + (tid >> 2);
    int c0 = (tid & 3) * 5;
    float acc[5];
#pragma unroll
    for (int j = 0; j < 5; ++j) acc[j] = b2[c0 + j];
    const float* orow = o + (long)r * 512;
    for (int i = 0; i < 512; ++i) {
        float v = orow[i];
#pragma unroll
        for (int j = 0; j < 5; ++j) acc[j] += v * ws[i * 20 + c0 + j];
    }
#pragma unroll
    for (int j = 0; j < 5; ++j) out[r * 20 + c0 + j] = acc[j];
}

extern "C" void kernel_launch(void* const* d_in, const int* in_sizes, int n_in,
                              void* d_out, int out_size, void* d_ws, size_t ws_size,
                              hipStream_t stream) {
    const float* wifi    = (const float*)d_in[0];
    const float* rfid    = (const float*)d_in[1];
    const float* gate_w1 = (const float*)d_in[2];
    const float* gate_b1 = (const float*)d_in[3];
    const float* gln_g   = (const float*)d_in[4];
    const float* gln_b   = (const float*)d_in[5];
    const float* gate_w2 = (const float*)d_in[6];
    const float* gate_b2 = (const float*)d_in[7];
    const float* exp_w1  = (const float*)d_in[8];
    const float* exp_b1  = (const float*)d_in[9];
    const float* bn1g    = (const float*)d_in[10];
    const float* bn1b    = (const float*)d_in[11];
    const float* bn1m    = (const float*)d_in[12];
    const float* bn1v    = (const float*)d_in[13];
    const float* exp_w2  = (const float*)d_in[14];
    const float* exp_b2  = (const float*)d_in[15];
    const float* bn2g    = (const float*)d_in[16];
    const float* bn2b    = (const float*)d_in[17];
    const float* bn2m    = (const float*)d_in[18];
    const float* bn2v    = (const float*)d_in[19];
    const float* fin_w1  = (const float*)d_in[20];
    const float* fin_b1  = (const float*)d_in[21];
    const float* fbng    = (const float*)d_in[22];
    const float* fbnb    = (const float*)d_in[23];
    const float* fbnm    = (const float*)d_in[24];
    const float* fbnv    = (const float*)d_in[25];
    const float* fin_w2  = (const float*)d_in[26];
    const float* fin_b2  = (const float*)d_in[27];
    float* out = (float*)d_out;

    const size_t MBy = 1u << 20;
    char* W = (char*)d_ws;
    float*          combined = (float*)         (W + 0);
    unsigned short* cbf      = (unsigned short*)(W + 8 * MBy);
    unsigned short* w1t      = (unsigned short*)(W + 12 * MBy);
    unsigned short* fusedb   = (unsigned short*)(W + 12 * MBy);   // after w1t dead
    float*          obuf     = (float*)         (W + 20 * MBy);   // after w1t dead
    unsigned short* w2t      = (unsigned short*)(W + 29 * MBy);
    float*          wq       = (float*)         (W + 61 * MBy);
    int*            rows     = (int*)           (W + 61 * MBy + (1 << 16));
    int*            counts   = (int*)           (W + 61 * MBy + (1 << 16) + (1 << 18));
    int*            wl       = (int*)           (W + 61 * MBy + (1 << 16) + (1 << 18) + 256);
    unsigned int*   topk     = (unsigned int*)  (W + 61 * MBy + (7 << 16));   // 16KB
    float*          w2tg     = (float*)         (W + 62 * MBy);
    unsigned short* fw1t     = (unsigned short*)(W + 63 * MBy);
    unsigned short* h1bf     = (unsigned short*)(W + 65 * MBy);
    unsigned short* cbf3     = (unsigned short*)(W + 65 * MBy);   // dead before h1bf written
    unsigned short* w1t3     = (unsigned short*)(W + 77 * MBy);   // dead before h1bf written
    float*          gbuf     = (float*)         (W + 99 * MBy);
    unsigned short* h2b      = (unsigned short*)(W + 99 * MBy);   // after gbuf dead

    concat_kernel<<<2048, 256, 0, stream>>>((const float4*)wifi, (const float4*)rfid,
                                            (float4*)combined, (ushort4*)cbf,
                                            (ushort4*)cbf3);

    // weight transposes fp32 [K][N] -> bf16 [N][K]
    transpose_f2b<<<dim3(16, 8, 16), 256, 0, stream>>>(exp_w1, w1t, 512, 1024);
    transpose_f2b<<<dim3(16, 16, 16), 256, 0, stream>>>(exp_w2, w2t, 1024, 1024);
    transpose_f2b<<<dim3(8, 16, 1), 256, 0, stream>>>(fin_w1, fw1t, 1024, 512);
    // gate_w1 -> bf16x3 [1024][1536] rows [hi | hi | lo]
    transpose_f2b_hilo<<<dim3(16, 8, 1), 256, 0, stream>>>(gate_w1, w1t3, 512, 1024);
    // gate_w2 [1024][16] -> [16][1024] fp32 for coalesced GEMV
    transpose_w2g<<<64, 256, 0, stream>>>(gate_w2, w2tg);

    // gate GEMM1 (dense, bf16x3 split-precision MFMA, K'=1536):
    //   cbf3 [hi|lo|hi] x w1t3 [hi|hi|lo] = Ahi.Whi + Alo.Whi + Ahi.Wlo
    // PLAIN epilogue: +bias, fp32 out -> gbuf. Grid: x=m-chunk drives XCD.
    mfma_gemm<0, false, false, false, true><<<dim3(64, 1, 16), 256, 0, stream>>>(
        cbf3, 1536, w1t3, 0, gate_b1,
        nullptr, nullptr, nullptr, nullptr, 0,
        gbuf, 1024, nullptr, nullptr, nullptr, 4096);

    // wave-per-row LN/GELU/logits/softmax/top4 (no barriers, no LDS, no atomics)
    ln_topk_wave<<<1024, 256, 0, stream>>>(gbuf, gln_g, gln_b, w2tg, gate_b2,
                                           wq, topk);
    // atomic-free scatter: rows/counts per expert
    compact_kernel<<<16, 256, 0, stream>>>(topk, rows, counts);
    build_wl_kernel<<<1, 256, 0, stream>>>(counts, wl);

    // expert GEMM1 (XCD worklist, bf16 MFMA, K=512): cbf rows -> h1bf[slot]
    mfma_gemm<2, true, true, true><<<dim3(8 * WLG, 1, 1), 256, 0, stream>>>(
        cbf, 512, w1t, (long)512 * 1024, exp_b1,
        bn1g, bn1b, bn1m, bn1v, 1024,
        h1bf, 1024, rows, counts, wl, 4096);

    // expert GEMM2 (XCD worklist, bf16 MFMA, K=1024): h1bf[slot] -> h2b[slot]
    mfma_gemm<0, true, true, true><<<dim3(8 * WLG, 1, 1), 256, 0, stream>>>(
        h1bf, 1024, w2t, (long)1024 * 1024, exp_b2,
        bn2g, bn2b, bn2m, bn2v, 1024,
        h2b, 1024, rows, counts, wl, 4096);

    combine_bf_kernel<<<4096, 256, 0, stream>>>((const ushort4*)h2b, wq, (ushort4*)fusedb);

    // final GEMM1 (dense, bf16 MFMA): fusedb -> obuf fp32, BN+GELU
    mfma_gemm<0, false, false, false><<<dim3(64, 1, 8), 256, 0, stream>>>(
        fusedb, 1024, fw1t, 0, fin_b1,
        fbng, fbnb, fbnm, fbnv, 0,
        obuf, 512, nullptr, nullptr, nullptr, 4096);

    fin2_kernel<<<64, 256, 0, stream>>>(obuf, fin_w2, fin_b2, out);
}

// Round 8
// 424.527 us; speedup vs baseline: 1.7438x; 1.0646x over previous
//
#include <hip/hip_runtime.h>

// MoE_77644418777543 — round 15.
// r14 post-mortem: occupancy theory falsified (occ 31->47% but eG2 71->81us).
// Series re-read: r0 LINEAR worklist eG2 = 66.8us @ occ 38.5% beats r11's
// XCD-grouped 70.9 @ 31% — the bid&7->XCD heuristic cost occupancy (mapping
// undefined; sentinel/real imbalance) for a FETCH fix the kernel never
// needed (2.3TB/s << HBM). This round: revert mfma_gemm to exact r11 body,
// LINEAR worklist (x-inner: 8 consecutive blocks share an A-tile), and trim
// fixed overhead: parallel build_wl (was serial 2176-store loop), 2-pass
// 1-barrier compact (was 48 barriers/block), drop dead `combined` write.
//
// Workspace (MB = 2^20), aliased by liveness:
//   8-12M   cbf bf16                 (dead after expert GEMM1)
//   12-28M  w1t bf16 [16][1024][512] (dead after GEMM1) / fusedb@12M, obuf@20M after
//   29-61M  w2t bf16 [16][1024][1024](dead after GEMM2)
//   61M     wq / rows / counts / wl[2176] / topk u32[4096]@+384K
//   62M     w2tg fp32 [16][1024] (gate w2 transposed, 64KB)
//   63-64M  fw1t bf16 [512][1024]
//   65-97M  h1bf bf16 [16384][1024]  (written by expert GEMM1)
//     65-77M  cbf3 bf16 [4096][1536]  (dead after gate MFMA -> safe alias)
//     77-80M  w1t3 bf16 [1024][1536]  (dead after gate MFMA -> safe alias)
//   99-131M gbuf fp32 (dead after ln_topk) then h2b bf16 [16384][1024]

#define EPSN 1e-5f

typedef __attribute__((ext_vector_type(8))) short v8s;   // 8 bf16 (4 VGPRs)
typedef __attribute__((ext_vector_type(4))) float v4f;   // 4 fp32 acc

typedef const unsigned int __attribute__((address_space(1)))* gas_u32;
typedef unsigned int __attribute__((address_space(3)))* las_u32;

__device__ __forceinline__ void glds16(const void* g, const void* l) {
    __builtin_amdgcn_global_load_lds((gas_u32)(uintptr_t)g, (las_u32)(uintptr_t)l, 16, 0, 0);
}

__device__ __forceinline__ float gelu_f(float x) {
    return 0.5f * x * (1.0f + erff(x * 0.70710678118654752440f));
}
__device__ __forceinline__ unsigned short f2bf(float x) {
    unsigned int u = __float_as_uint(x);
    u += 0x7fffu + ((u >> 16) & 1u);
    return (unsigned short)(u >> 16);
}
__device__ __forceinline__ float bf2f(unsigned short u) {
    return __uint_as_float(((unsigned int)u) << 16);
}

// concat wifi|rfid -> bf16 copy for expert GEMM1, and bf16x3 row
// [hi(512) | lo(512) | hi(512)] for the split-precision gate GEMM.
// (fp32 combined copy removed — it was dead.)
__global__ __launch_bounds__(256) void concat_kernel(const float4* __restrict__ wifi,
                                                     const float4* __restrict__ rfid,
                                                     ushort4* __restrict__ cbf,
                                                     ushort4* __restrict__ cbf3) {
    int gid = blockIdx.x * 256 + threadIdx.x;   // 4096 * 128
    int b = gid >> 7, c = gid & 127;
    float4 v = (c < 64) ? wifi[b * 64 + c] : rfid[b * 64 + (c - 64)];
    ushort4 hi, lo;
    hi.x = f2bf(v.x); hi.y = f2bf(v.y); hi.z = f2bf(v.z); hi.w = f2bf(v.w);
    lo.x = f2bf(v.x - bf2f(hi.x));
    lo.y = f2bf(v.y - bf2f(hi.y));
    lo.z = f2bf(v.z - bf2f(hi.z));
    lo.w = f2bf(v.w - bf2f(hi.w));
    cbf[gid] = hi;
    const long r3 = (long)b * 384 + c;          // 1536 ush row = 384 ushort4
    cbf3[r3]       = hi;
    cbf3[r3 + 128] = lo;
    cbf3[r3 + 256] = hi;
}

// in: per-expert [K][N] fp32 -> out: per-expert [N][K] bf16 (transpose+convert)
__global__ __launch_bounds__(256) void transpose_f2b(const float* __restrict__ in,
                                                     unsigned short* __restrict__ out,
                                                     int K, int N) {
    __shared__ float t[64][65];
    int e = blockIdx.z;
    int n0 = blockIdx.x << 6, k0 = blockIdx.y << 6;
    const float* ie = in + (long)e * K * N;
    unsigned short* oe = out + (long)e * N * K;
    int tid = threadIdx.x;
    int rr = tid >> 4, cc = (tid & 15) << 2;
#pragma unroll
    for (int p = 0; p < 4; ++p) {
        int k = (p << 4) + rr;
        float4 v = *(const float4*)(ie + (long)(k0 + k) * N + n0 + cc);
        t[k][cc + 0] = v.x; t[k][cc + 1] = v.y; t[k][cc + 2] = v.z; t[k][cc + 3] = v.w;
    }
    __syncthreads();
    int n = tid >> 2, kq = (tid & 3) << 4;
    unsigned short u[16];
#pragma unroll
    for (int j = 0; j < 16; ++j) u[j] = f2bf(t[kq + j][n]);
    uint4* dst = (uint4*)(oe + (long)(n0 + n) * K + k0 + kq);
    dst[0] = ((const uint4*)u)[0];
    dst[1] = ((const uint4*)u)[1];
}

// gate_w1 [K=512][N=1024] fp32 -> w1t3 [N][3K=1536] bf16, rows [hi | hi | lo]
__global__ __launch_bounds__(256) void transpose_f2b_hilo(const float* __restrict__ in,
                                                          unsigned short* __restrict__ out,
                                                          int K, int N) {
    __shared__ float t[64][65];
    int n0 = blockIdx.x << 6, k0 = blockIdx.y << 6;
    int tid = threadIdx.x;
    int rr = tid >> 4, cc = (tid & 15) << 2;
#pragma unroll
    for (int p = 0; p < 4; ++p) {
        int k = (p << 4) + rr;
        float4 v = *(const float4*)(in + (long)(k0 + k) * N + n0 + cc);
        t[k][cc + 0] = v.x; t[k][cc + 1] = v.y; t[k][cc + 2] = v.z; t[k][cc + 3] = v.w;
    }
    __syncthreads();
    int n = tid >> 2, kq = (tid & 3) << 4;
    unsigned short uh[16], ul[16];
#pragma unroll
    for (int j = 0; j < 16; ++j) {
        float x = t[kq + j][n];
        unsigned short h = f2bf(x);
        uh[j] = h;
        ul[j] = f2bf(x - bf2f(h));
    }
    unsigned short* dh = out + (long)(n0 + n) * (3 * K) + k0 + kq;
    ((uint4*)dh)[0]           = ((const uint4*)uh)[0];
    ((uint4*)dh)[1]           = ((const uint4*)uh)[1];
    ((uint4*)(dh + K))[0]     = ((const uint4*)uh)[0];
    ((uint4*)(dh + K))[1]     = ((const uint4*)uh)[1];
    ((uint4*)(dh + 2 * K))[0] = ((const uint4*)ul)[0];
    ((uint4*)(dh + 2 * K))[1] = ((const uint4*)ul)[1];
}

// gate_w2 fp32 [1024][16] -> w2tg fp32 [16][1024] (64KB; coalesced reads)
__global__ __launch_bounds__(256) void transpose_w2g(const float* __restrict__ in,
                                                     float* __restrict__ out) {
    int gid = blockIdx.x * 256 + threadIdx.x;   // 16384
    int c = gid >> 4, e = gid & 15;
    out[e * 1024 + c] = in[gid];
}

// Fused LN+GELU -> 16 logits -> softmax -> top4 -> renorm.
// ONE WAVE PER ROW: no barriers, no LDS, no atomics. Writes 4 weights +
// packed top-4 ids (u32). Scatter is done by compact_kernel.
__global__ __launch_bounds__(256) void ln_topk_wave(
    const float* __restrict__ g,
    const float* __restrict__ lng, const float* __restrict__ lnb,
    const float* __restrict__ w2t, const float* __restrict__ b2,
    float* __restrict__ wout, unsigned int* __restrict__ topk)
{
    const int tid = threadIdx.x;
    const int lane = tid & 63;
    const int b = (blockIdx.x << 2) + (tid >> 6);
    const float* row = g + (long)b * 1024;
    const int c0 = lane << 2;

    float4 xv[4];
    float s = 0.f, q = 0.f;
#pragma unroll
    for (int p = 0; p < 4; ++p) {
        float4 v = *(const float4*)(row + (p << 8) + c0);
        xv[p] = v;
        s += v.x + v.y + v.z + v.w;
        q += v.x * v.x + v.y * v.y + v.z * v.z + v.w * v.w;
    }
#pragma unroll
    for (int mk = 32; mk >= 1; mk >>= 1) {
        s += __shfl_xor(s, mk);
        q += __shfl_xor(q, mk);
    }
    const float mu = s * (1.0f / 1024.0f);
    const float var = q * (1.0f / 1024.0f) - mu * mu;
    const float rstd = rsqrtf(var + EPSN);

#pragma unroll
    for (int p = 0; p < 4; ++p) {
        float4 gv = *(const float4*)(lng + (p << 8) + c0);
        float4 bv = *(const float4*)(lnb + (p << 8) + c0);
        xv[p].x = gelu_f((xv[p].x - mu) * rstd * gv.x + bv.x);
        xv[p].y = gelu_f((xv[p].y - mu) * rstd * gv.y + bv.y);
        xv[p].z = gelu_f((xv[p].z - mu) * rstd * gv.z + bv.z);
        xv[p].w = gelu_f((xv[p].w - mu) * rstd * gv.w + bv.w);
    }

    // logits GEMV: a[e] += dot(xv[p], w2t[e][p*256 + lane*4 .. +3])
    float a[16];
#pragma unroll
    for (int i = 0; i < 16; ++i) a[i] = 0.f;
#pragma unroll
    for (int p = 0; p < 4; ++p) {
        const float4 x4 = xv[p];
        const float* wp = w2t + (p << 8) + c0;
#pragma unroll
        for (int e = 0; e < 16; ++e) {
            const float4 w = *(const float4*)(wp + (e << 10));
            a[e] = fmaf(x4.x, w.x, a[e]);
            a[e] = fmaf(x4.y, w.y, a[e]);
            a[e] = fmaf(x4.z, w.z, a[e]);
            a[e] = fmaf(x4.w, w.w, a[e]);
        }
    }
#pragma unroll
    for (int mk = 32; mk >= 1; mk >>= 1) {
#pragma unroll
        for (int i = 0; i < 16; ++i) a[i] += __shfl_xor(a[i], mk);
    }
#pragma unroll
    for (int i = 0; i < 16; ++i) a[i] += b2[i];

    // softmax (all lanes redundantly; uniform, no divergence)
    float m = a[0];
#pragma unroll
    for (int i = 1; i < 16; ++i) m = fmaxf(m, a[i]);
    float Z = 0.f;
#pragma unroll
    for (int i = 0; i < 16; ++i) { a[i] = expf(a[i] - m); Z += a[i]; }
    const float iZ = 1.0f / Z;
#pragma unroll
    for (int i = 0; i < 16; ++i) a[i] *= iZ;

    // top-4 with index tracking; static indexing only (rule #20)
    float tv0, tv1, tv2, tv3;
    int ti0, ti1, ti2, ti3;
#define PICK(TV, TI)                                                         \
    {   float bv = a[0]; int bi = 0;                                         \
        _Pragma("unroll")                                                    \
        for (int i = 1; i < 16; ++i) {                                       \
            bool t = a[i] > bv; bv = t ? a[i] : bv; bi = t ? i : bi;         \
        }                                                                    \
        TV = bv; TI = bi;                                                    \
        _Pragma("unroll")                                                    \
        for (int i = 0; i < 16; ++i) a[i] = (i == bi) ? -1.f : a[i];         \
    }
    PICK(tv0, ti0)
    PICK(tv1, ti1)
    PICK(tv2, ti2)
    PICK(tv3, ti3)
#undef PICK

    const float q1 = expf(tv1 - tv0);
    const float q2 = expf(tv2 - tv0);
    const float q3 = expf(tv3 - tv0);
    const float iZ2 = 1.0f / (1.0f + q1 + q2 + q3);
    if (lane < 4) {
        float wk = (lane == 0) ? 1.f : (lane == 1) ? q1 : (lane == 2) ? q2 : q3;
        wout[(b << 2) + lane] = wk * iZ2;
    }
    if (lane == 0)
        topk[b] = (unsigned)ti0 | ((unsigned)ti1 << 8) |
                  ((unsigned)ti2 << 16) | ((unsigned)ti3 << 24);
}

// Atomic-free scatter, 2-pass, ONE barrier: wave wid owns rows
// wid*1024 .. wid*1024+1023. Pass1 counts matches (ballot+popc, in-reg);
// barrier; exclusive scan of 4 wave totals; pass2 rewalks (L2-hot) and
// scatters at running in-register offsets. Row-ascending order per expert.
__global__ __launch_bounds__(256) void compact_kernel(const unsigned int* __restrict__ topk,
                                                      int* __restrict__ rows_,
                                                      int* __restrict__ counts) {
    const int e = blockIdx.x;           // 16
    const int tid = threadIdx.x;
    const int wid = tid >> 6, lane = tid & 63;
    __shared__ int wtot[4];

    int cw = 0;
#pragma unroll
    for (int it = 0; it < 16; ++it) {
        const int r = (wid << 10) + (it << 6) + lane;
        const unsigned int w = topk[r];
        bool hit = (((w) & 255u) == (unsigned)e) | (((w >> 8) & 255u) == (unsigned)e) |
                   (((w >> 16) & 255u) == (unsigned)e) | (((w >> 24) & 255u) == (unsigned)e);
        cw += __popcll(__ballot(hit));
    }
    if (lane == 0) wtot[wid] = cw;
    __syncthreads();
    int base = 0;
#pragma unroll
    for (int j = 0; j < 4; ++j) base += (j < wid) ? wtot[j] : 0;
    if (tid == 0) counts[e] = wtot[0] + wtot[1] + wtot[2] + wtot[3];

    int off = base;
#pragma unroll
    for (int it = 0; it < 16; ++it) {
        const int r = (wid << 10) + (it << 6) + lane;
        const unsigned int w = topk[r];
        int slot = -1;
        if (((w) & 255u) == (unsigned)e)       slot = (r << 2) | 0;
        if (((w >> 8) & 255u) == (unsigned)e)  slot = (r << 2) | 1;
        if (((w >> 16) & 255u) == (unsigned)e) slot = (r << 2) | 2;
        if (((w >> 24) & 255u) == (unsigned)e) slot = (r << 2) | 3;
        const unsigned long long m = __ballot(slot >= 0);
        if (slot >= 0) {
            const int pref = __popcll(m & ((1ull << lane) - 1ull));
            rows_[(e << 12) + off + pref] = slot;
        }
        off += __popcll(m);
    }
}

// LINEAR worklist (no XCD grouping — r0-proven better: occ 38.5% vs 31%).
// Entries (e<<16)|(mc<<4)|x, mc-outer x-inner: 8 consecutive blocks share an
// A-tile. Parallel build: thread t handles expert t>>4, stride-16 entries.
#define WL_MAX 2176   // sum ceil(cnt/64) <= 272, x8
__global__ __launch_bounds__(256) void build_wl_kernel(const int* __restrict__ counts,
                                                       int* __restrict__ wl) {
    int t = threadIdx.x;
    for (int i = t; i < WL_MAX; i += 256) wl[i] = -1;
    __syncthreads();
    int off[17];
    off[0] = 0;
#pragma unroll
    for (int e = 0; e < 16; ++e) off[e + 1] = off[e] + (((counts[e] + 63) >> 6) << 3);
    const int e = t >> 4, s = t & 15;
    const int ne = ((counts[e] + 63) >> 6) << 3;
    for (int i = s; i < ne; i += 16) {
        int mc = i >> 3, x = i & 7;
        wl[off[e] + i] = (e << 16) | (mc << 4) | x;
    }
}

// bf16 MFMA GEMM (exact r11 body): 64x128 tile, BK=64, 256 threads (4 waves
// 2x2: 32x64 quadrants), 16 MFMA/wave/iter, serial 2-barrier loop.
// LDS stage: A [64][64] + B [128][64] bf16, 24KB, k-chunk XOR swizzle:
//   chunk kc of row r stored at position kc^(r&7) -> ds_read_b128 2-way (free).
// glds16 dest is lane-contiguous; swizzle applied via SOURCE pointer.
// WL: 1-D grid, linear worklist. !WL: grid (x=m-chunk, y=e, z=n-chunk).
// OUTBF epilogue: BN+GELU -> bf16 LDS tile -> vectorized 16B row stores.
// PLAIN epilogue: bias only, fp32 out (bf16x3 gate GEMM).
template<int ASHIFT, bool GATHER, bool OUTBF, bool WL, bool PLAIN = false>
__global__ __launch_bounds__(256) void mfma_gemm(
    const unsigned short* __restrict__ A, int K,
    const unsigned short* __restrict__ Wt, long wstride,
    const float* __restrict__ bias,
    const float* __restrict__ bng, const float* __restrict__ bnb,
    const float* __restrict__ bnm, const float* __restrict__ bnv,
    int pstride,
    void* __restrict__ outv, int ldo,
    const int* __restrict__ rows_, const int* __restrict__ counts,
    const int* __restrict__ wl, int M)
{
    constexpr int TM = 64;
    int e, m0, n0;
    if constexpr (WL) {
        int w = wl[blockIdx.x];
        if (w < 0) return;
        e = w >> 16;
        m0 = ((w >> 4) & 0xfff) << 6;
        n0 = (w & 15) << 7;
    } else {
        e = blockIdx.y;
        m0 = blockIdx.x * TM;
        n0 = blockIdx.z << 7;
    }
    const int cnt = GATHER ? counts[e] : M;

    constexpr int AB_USH = 64 * 64 + 128 * 64;          // 12288 ush = 24KB
    constexpr int OL_STRIDE = 136;                      // 272B rows (16B-aligned)
    constexpr int OL_USH = OUTBF ? TM * OL_STRIDE : 0;  // 8704 ush (reuses stage)
    constexpr int SM_USH = (OL_USH > AB_USH) ? OL_USH : AB_USH;
    __shared__ __align__(16) unsigned short smem[SM_USH];
    unsigned short* Als = smem;            // [64 rows][64 k] (swizzled chunks)
    unsigned short* Bls = smem + 64 * 64;  // [128 rows][64 k]
    __shared__ int rid[TM];
    __shared__ int ain[TM];

    const int tid = threadIdx.x;
    if (tid < TM) {
        int i = m0 + tid;
        int pk, ai;
        if (GATHER) {
            if (i < cnt) { pk = rows_[(e << 12) + i]; ai = pk >> ASHIFT; }
            else { pk = -1; ai = 0; }
        } else { pk = i; ai = i; }
        rid[tid] = pk;
        ain[tid] = ai;
    }
    __syncthreads();

    const int wave = tid >> 6, lane = tid & 63;
    const int wm = (wave >> 1) << 5, wn = (wave & 1) << 6;   // 2x2 waves: m 0/32, n 0/64
    const int lrow = lane & 15, kch = lane >> 4;
    const int wb = wave << 9;                                // per-wave stage base (ush)

    // staging source map: slot-local row srow=tid>>3, dest chunk pos spos=tid&7,
    // source chunk skc = spos ^ (srow&7)   [XOR swizzle]
    const int srow = tid >> 3, spos = tid & 7;
    const int skc8 = (spos ^ (srow & 7)) << 3;

    const unsigned short* apa = A + (long)ain[srow] * K + skc8;
    const unsigned short* apb = A + (long)ain[32 + srow] * K + skc8;
    const unsigned short* Wte = Wt + (long)e * wstride;
    const unsigned short* bp0 = Wte + (long)(n0 + srow) * K + skc8;
    const unsigned short* bp1 = Wte + (long)(n0 + 32 + srow) * K + skc8;
    const unsigned short* bp2 = Wte + (long)(n0 + 64 + srow) * K + skc8;
    const unsigned short* bp3 = Wte + (long)(n0 + 96 + srow) * K + skc8;

    v4f acc[2][4] = {};

    const int nk = K >> 6;
    for (int it = 0; it < nk; ++it) {
        glds16(apa, Als + wb);
        glds16(apb, Als + 2048 + wb);
        glds16(bp0, Bls + wb);
        glds16(bp1, Bls + 2048 + wb);
        glds16(bp2, Bls + 4096 + wb);
        glds16(bp3, Bls + 6144 + wb);
        apa += 64; apb += 64; bp0 += 64; bp1 += 64; bp2 += 64; bp3 += 64;
        __syncthreads();

#pragma unroll
        for (int s = 0; s < 2; ++s) {
            const int kc = (s << 2) | kch;
            v8s av[2], bv[4];
#pragma unroll
            for (int f = 0; f < 2; ++f) {
                const int row = wm + (f << 4) + lrow;
                av[f] = *(const v8s*)(Als + row * 64 + ((kc ^ (row & 7)) << 3));
            }
#pragma unroll
            for (int f = 0; f < 4; ++f) {
                const int row = wn + (f << 4) + lrow;
                bv[f] = *(const v8s*)(Bls + row * 64 + ((kc ^ (row & 7)) << 3));
            }
#pragma unroll
            for (int fi = 0; fi < 2; ++fi)
#pragma unroll
                for (int fj = 0; fj < 4; ++fj)
                    acc[fi][fj] = __builtin_amdgcn_mfma_f32_16x16x32_bf16(
                        av[fi], bv[fj], acc[fi][fj], 0, 0, 0);
        }
        __syncthreads();
    }

    // epilogue: C/D layout col=lane&15, row=(lane>>4)*4+reg
    if constexpr (OUTBF) {
        unsigned short* Ols = smem;   // stage buffers dead after final barrier
#pragma unroll
        for (int fj = 0; fj < 4; ++fj) {
            const int c = wn + (fj << 4) + lrow;
            const int pc = e * pstride + n0 + c;
            const float bs = bias[pc];
            const float sc = bng[pc] * rsqrtf(bnv[pc] + EPSN);
            const float mn = bnm[pc], bb = bnb[pc];
#pragma unroll
            for (int fi = 0; fi < 2; ++fi) {
#pragma unroll
                for (int r = 0; r < 4; ++r) {
                    const int lr = wm + (fi << 4) + (kch << 2) + r;
                    float x = acc[fi][fj][r] + bs;
                    x = (x - mn) * sc + bb;
                    x = gelu_f(x);
                    Ols[lr * OL_STRIDE + c] = f2bf(x);
                }
            }
        }
        __syncthreads();
        const int rl = tid >> 4;
        const int c8 = (tid & 15) << 3;
#pragma unroll
        for (int p = 0; p < TM / 16; ++p) {
            const int row = (p << 4) + rl;
            const int orow = rid[row];
            if (orow >= 0) {
                uint4 v = *(const uint4*)(Ols + row * OL_STRIDE + c8);
                *(uint4*)((unsigned short*)outv + (long)orow * ldo + n0 + c8) = v;
            }
        }
    } else {
#pragma unroll
        for (int fj = 0; fj < 4; ++fj) {
            const int c = n0 + wn + (fj << 4) + lrow;
            const int pc = e * pstride + c;
            const float bs = bias[pc];
            float sc = 1.f, mn = 0.f, bb = 0.f;
            if constexpr (!PLAIN) {
                sc = bng[pc] * rsqrtf(bnv[pc] + EPSN);
                mn = bnm[pc]; bb = bnb[pc];
            }
#pragma unroll
            for (int fi = 0; fi < 2; ++fi) {
#pragma unroll
                for (int r = 0; r < 4; ++r) {
                    const int lr = wm + (fi << 4) + (kch << 2) + r;
                    const int orow = rid[lr];
                    if (orow < 0) continue;
                    float x = acc[fi][fj][r] + bs;
                    if constexpr (!PLAIN) {
                        x = (x - mn) * sc + bb;
                        x = gelu_f(x);
                    }
                    ((float*)outv)[(long)orow * ldo + c] = x;
                }
            }
        }
    }
}

// weighted top-4 combine, bf16 in -> bf16 out
__global__ __launch_bounds__(256) void combine_bf_kernel(const ushort4* __restrict__ h2b,
                                                         const float* __restrict__ w,
                                                         ushort4* __restrict__ fusedb) {
    int gid = blockIdx.x * 256 + threadIdx.x;  // 4096*256
    int b = gid >> 8, c = gid & 255;
    float a0 = 0.f, a1 = 0.f, a2 = 0.f, a3 = 0.f;
#pragma unroll
    for (int k = 0; k < 4; ++k) {
        float wk = w[b * 4 + k];
        ushort4 v = h2b[(long)(b * 4 + k) * 256 + c];
        a0 += wk * bf2f(v.x); a1 += wk * bf2f(v.y);
        a2 += wk * bf2f(v.z); a3 += wk * bf2f(v.w);
    }
    ushort4 o;
    o.x = f2bf(a0); o.y = f2bf(a1); o.z = f2bf(a2); o.w = f2bf(a3);
    fusedb[gid] = o;
}

__global__ __launch_bounds__(256) void fin2_kernel(const float* __restrict__ o,
                                                   const float* __restrict__ w2,
                                                   const float* __restrict__ b2,
                                                   float* __restrict__ out) {
    __shared__ float ws[512 * 20];
    int tid = threadIdx.x;
    for (int i = tid; i < 512 * 20; i += 256) ws[i] = w2[i];
    __syncthreads();
    int r = blockIdx.x * 64 + (tid >> 2);
    int c0 = (tid & 3) * 5;
    float acc[5];
#pragma unroll
    for (int j = 0; j < 5; ++j) acc[j] = b2[c0 + j];
    const float* orow = o + (long)r * 512;
    for (int i = 0; i < 512; ++i) {
        float v = orow[i];
#pragma unroll
        for (int j = 0; j < 5; ++j) acc[j] += v * ws[i * 20 + c0 + j];
    }
#pragma unroll
    for (int j = 0; j < 5; ++j) out[r * 20 + c0 + j] = acc[j];
}

extern "C" void kernel_launch(void* const* d_in, const int* in_sizes, int n_in,
                              void* d_out, int out_size, void* d_ws, size_t ws_size,
                              hipStream_t stream) {
    const float* wifi    = (const float*)d_in[0];
    const float* rfid    = (const float*)d_in[1];
    const float* gate_w1 = (const float*)d_in[2];
    const float* gate_b1 = (const float*)d_in[3];
    const float* gln_g   = (const float*)d_in[4];
    const float* gln_b   = (const float*)d_in[5];
    const float* gate_w2 = (const float*)d_in[6];
    const float* gate_b2 = (const float*)d_in[7];
    const float* exp_w1  = (const float*)d_in[8];
    const float* exp_b1  = (const float*)d_in[9];
    const float* bn1g    = (const float*)d_in[10];
    const float* bn1b    = (const float*)d_in[11];
    const float* bn1m    = (const float*)d_in[12];
    const float* bn1v    = (const float*)d_in[13];
    const float* exp_w2  = (const float*)d_in[14];
    const float* exp_b2  = (const float*)d_in[15];
    const float* bn2g    = (const float*)d_in[16];
    const float* bn2b    = (const float*)d_in[17];
    const float* bn2m    = (const float*)d_in[18];
    const float* bn2v    = (const float*)d_in[19];
    const float* fin_w1  = (const float*)d_in[20];
    const float* fin_b1  = (const float*)d_in[21];
    const float* fbng    = (const float*)d_in[22];
    const float* fbnb    = (const float*)d_in[23];
    const float* fbnm    = (const float*)d_in[24];
    const float* fbnv    = (const float*)d_in[25];
    const float* fin_w2  = (const float*)d_in[26];
    const float* fin_b2  = (const float*)d_in[27];
    float* out = (float*)d_out;

    const size_t MBy = 1u << 20;
    char* W = (char*)d_ws;
    unsigned short* cbf      = (unsigned short*)(W + 8 * MBy);
    unsigned short* w1t      = (unsigned short*)(W + 12 * MBy);
    unsigned short* fusedb   = (unsigned short*)(W + 12 * MBy);   // after w1t dead
    float*          obuf     = (float*)         (W + 20 * MBy);   // after w1t dead
    unsigned short* w2t      = (unsigned short*)(W + 29 * MBy);
    float*          wq       = (float*)         (W + 61 * MBy);
    int*            rows     = (int*)           (W + 61 * MBy + (1 << 16));
    int*            counts   = (int*)           (W + 61 * MBy + (1 << 16) + (1 << 18));
    int*            wl       = (int*)           (W + 61 * MBy + (1 << 16) + (1 << 18) + 256);
    unsigned int*   topk     = (unsigned int*)  (W + 61 * MBy + (6 << 16));   // 16KB
    float*          w2tg     = (float*)         (W + 62 * MBy);
    unsigned short* fw1t     = (unsigned short*)(W + 63 * MBy);
    unsigned short* h1bf     = (unsigned short*)(W + 65 * MBy);
    unsigned short* cbf3     = (unsigned short*)(W + 65 * MBy);   // dead before h1bf written
    unsigned short* w1t3     = (unsigned short*)(W + 77 * MBy);   // dead before h1bf written
    float*          gbuf     = (float*)         (W + 99 * MBy);
    unsigned short* h2b      = (unsigned short*)(W + 99 * MBy);   // after gbuf dead

    concat_kernel<<<2048, 256, 0, stream>>>((const float4*)wifi, (const float4*)rfid,
                                            (ushort4*)cbf, (ushort4*)cbf3);

    // weight transposes fp32 [K][N] -> bf16 [N][K]
    transpose_f2b<<<dim3(16, 8, 16), 256, 0, stream>>>(exp_w1, w1t, 512, 1024);
    transpose_f2b<<<dim3(16, 16, 16), 256, 0, stream>>>(exp_w2, w2t, 1024, 1024);
    transpose_f2b<<<dim3(8, 16, 1), 256, 0, stream>>>(fin_w1, fw1t, 1024, 512);
    // gate_w1 -> bf16x3 [1024][1536] rows [hi | hi | lo]
    transpose_f2b_hilo<<<dim3(16, 8, 1), 256, 0, stream>>>(gate_w1, w1t3, 512, 1024);
    // gate_w2 [1024][16] -> [16][1024] fp32 for coalesced GEMV
    transpose_w2g<<<64, 256, 0, stream>>>(gate_w2, w2tg);

    // gate GEMM1 (dense, bf16x3 split-precision MFMA, K'=1536):
    //   cbf3 [hi|lo|hi] x w1t3 [hi|hi|lo] = Ahi.Whi + Alo.Whi + Ahi.Wlo
    // PLAIN epilogue: +bias, fp32 out -> gbuf.
    mfma_gemm<0, false, false, false, true><<<dim3(64, 1, 8), 256, 0, stream>>>(
        cbf3, 1536, w1t3, 0, gate_b1,
        nullptr, nullptr, nullptr, nullptr, 0,
        gbuf, 1024, nullptr, nullptr, nullptr, 4096);

    // wave-per-row LN/GELU/logits/softmax/top4 (no barriers, no LDS, no atomics)
    ln_topk_wave<<<1024, 256, 0, stream>>>(gbuf, gln_g, gln_b, w2tg, gate_b2,
                                           wq, topk);
    // atomic-free scatter: rows/counts per expert (2-pass, 1 barrier)
    compact_kernel<<<16, 256, 0, stream>>>(topk, rows, counts);
    build_wl_kernel<<<1, 256, 0, stream>>>(counts, wl);

    // expert GEMM1 (linear worklist, bf16 MFMA, K=512): cbf rows -> h1bf[slot]
    mfma_gemm<2, true, true, true><<<dim3(WL_MAX, 1, 1), 256, 0, stream>>>(
        cbf, 512, w1t, (long)512 * 1024, exp_b1,
        bn1g, bn1b, bn1m, bn1v, 1024,
        h1bf, 1024, rows, counts, wl, 4096);

    // expert GEMM2 (linear worklist, bf16 MFMA, K=1024): h1bf[slot] -> h2b[slot]
    mfma_gemm<0, true, true, true><<<dim3(WL_MAX, 1, 1), 256, 0, stream>>>(
        h1bf, 1024, w2t, (long)1024 * 1024, exp_b2,
        bn2g, bn2b, bn2m, bn2v, 1024,
        h2b, 1024, rows, counts, wl, 4096);

    combine_bf_kernel<<<4096, 256, 0, stream>>>((const ushort4*)h2b, wq, (ushort4*)fusedb);

    // final GEMM1 (dense, bf16 MFMA): fusedb -> obuf fp32, BN+GELU
    mfma_gemm<0, false, false, false><<<dim3(64, 1, 4), 256, 0, stream>>>(
        fusedb, 1024, fw1t, 0, fin_b1,
        fbng, fbnb, fbnm, fbnv, 0,
        obuf, 512, nullptr, nullptr, nullptr, 4096);

    fin2_kernel<<<64, 256, 0, stream>>>(obuf, fin_w2, fin_b2, out);
}